// Round 6
// baseline (512.027 us; speedup 1.0000x reference)
//
#include <hip/hip_runtime.h>
#include <hip/hip_bf16.h>

constexpr int B_ = 2, HQ_ = 16, HP_ = 8, S_ = 2048, D_ = 64, DV_ = 128;
constexpr float LAMB0 = 0.8f;
constexpr float EPSV = 1e-5f;

constexpr int TQ = 64, TK = 32;
constexpr int KSTR = 72;  // shorts per K row (64+8) = 144 B
constexpr int VSTR = 40;  // shorts per V^T row (32+8) = 80 B

typedef __attribute__((ext_vector_type(8))) short bf16x8;
typedef __attribute__((ext_vector_type(4))) float f32x4;
typedef __attribute__((ext_vector_type(8))) float f32x8;

__device__ __forceinline__ unsigned short f2bf(float x) {
  __hip_bfloat16 h = __float2bfloat16(x);  // RNE; pairs into v_cvt_pk_bf16_f32
  unsigned short u;
  __builtin_memcpy(&u, &h, 2);
  return u;
}
__device__ __forceinline__ float bf2f(unsigned short h) {
  return __uint_as_float((unsigned)h << 16);
}
__device__ __forceinline__ unsigned pack2(unsigned short a, unsigned short b) {
  return (unsigned)a | ((unsigned)b << 16);
}
// Value-typed hi/lo split: NO pointers to locals -> guaranteed register-resident.
__device__ __forceinline__ void split8v(f32x8 x, bf16x8& hi, bf16x8& lo) {
  union { bf16x8 v; unsigned short s[8]; } H, L;
#pragma unroll
  for (int j = 0; j < 8; ++j) {
    unsigned short h = f2bf(x[j]);
    H.s[j] = h;
    L.s[j] = f2bf(x[j] - bf2f(h));
  }
  hi = H.v;
  lo = L.v;
}

// ---------------------------------------------------------------------------
// Differential flash attention, bf16x3 MFMA emulation.
// R6 = R5 structure with the scratch-spill bug fixed (value-typed splits):
// cooperative K+V staging, single-buffered 49.2 KB LDS -> 3 blocks/CU,
// issue-early global loads held in regs, swizzled V^T, per-wave P exchange,
// fused GroupNorm stats.
// ---------------------------------------------------------------------------
__launch_bounds__(256, 3)
__global__ void diffattn_fwd(const float* __restrict__ qg, const float* __restrict__ kg,
                             const float* __restrict__ vg,
                             const float* __restrict__ lq1, const float* __restrict__ lk1,
                             const float* __restrict__ lq2, const float* __restrict__ lk2,
                             float* __restrict__ Obuf, float* __restrict__ stats) {
  __shared__ short Kl[2][2][TK][KSTR];  // [head][hi/lo][k][d] 18.4 KB
  __shared__ short Vt[2][DV_][VSTR];    // [hi/lo][dv][k^swz]  20.5 KB
  __shared__ short Pex[4][32][40];      // per-wave P exchange 10.2 KB
  __shared__ float redbuf[8];

  const int tid = threadIdx.x;
  const int w = tid >> 6;
  const int l = tid & 63;
  const int g = l >> 4;
  const int li = l & 15;

  const int t = blockIdx.x;
  const int bh = t & 15;
  const int b = bh >> 3;
  const int hp = bh & 7;
  const int u = t >> 4;
  const int qt = (u & 1) ? (31 - (u >> 1)) : (u >> 1);  // causal load pairing
  const int q0 = qt * TQ;
  const int qw = q0 + w * 16;

  float d1 = 0.f, d2 = 0.f;
  for (int i = 0; i < D_; ++i) { d1 += lq1[i] * lk1[i]; d2 += lq2[i] * lk2[i]; }
  const float lam = __expf(d1) - __expf(d2) + LAMB0;

  // ---- Q fragments in registers, hi/lo split ----
  bf16x8 qhi[2][2], qlo[2][2];
#pragma unroll
  for (int h = 0; h < 2; ++h)
#pragma unroll
    for (int c = 0; c < 2; ++c) {
      const float* p = qg + (((size_t)b * HQ_ + 2 * hp + h) * S_ + qw + li) * D_ + c * 32 + g * 8;
      f32x8 x = *reinterpret_cast<const f32x8*>(p);  // 32B-aligned
      split8v(x, qhi[h][c], qlo[h][c]);
    }

  float mreg[2] = {0.f, 0.f};  // ghostmax init m=0, l=1 (implicit zero logit)
  float lreg[2] = {1.f, 1.f};
  const f32x4 zero4 = {0.f, 0.f, 0.f, 0.f};
  f32x4 Oacc[2][8];
#pragma unroll
  for (int h = 0; h < 2; ++h)
#pragma unroll
    for (int d = 0; d < 8; ++d) Oacc[h][d] = zero4;

  // staging roles
  const int khs = tid >> 7;   // K: head
  const int ktf = tid & 127;  //    128 threads cover 32x64 via f32x8 rows
  const float* kb0 = kg + ((size_t)b * HQ_ + 2 * hp + khs) * S_ * D_;
  const int vdv = tid & 127;  // V: dv lane
  const int vkq0 = tid >> 7;
  const float* vb0 = vg + ((size_t)b * HP_ + hp) * S_ * DV_ + vdv;
  const int vswz = ((vdv >> 3) & 3) << 3;

  f32x8 kregv[2];  // value-typed, register-resident across compute
  f32x8 vregv[2];

  auto issue_loads = [&](int k0) {
    const float* kb = kb0 + (size_t)k0 * D_;
#pragma unroll
    for (int it = 0; it < 2; ++it)
      kregv[it] = *reinterpret_cast<const f32x8*>(
          kb + (size_t)((ktf >> 3) + it * 16) * D_ + (ktf & 7) * 8);
    const float* vb = vb0 + (size_t)k0 * DV_;
#pragma unroll
    for (int it = 0; it < 2; ++it) {
      const int kb8 = vkq0 * 8 + it * 16;
#pragma unroll
      for (int j = 0; j < 8; ++j) vregv[it][j] = vb[(size_t)(kb8 + j) * DV_];
    }
  };

  auto write_tiles = [&]() {
#pragma unroll
    for (int it = 0; it < 2; ++it) {
      const int row = (ktf >> 3) + it * 16;
      const int col8 = (ktf & 7) * 8;
      bf16x8 hi, lo;
      split8v(kregv[it], hi, lo);
      *reinterpret_cast<bf16x8*>(&Kl[khs][0][row][col8]) = hi;
      *reinterpret_cast<bf16x8*>(&Kl[khs][1][row][col8]) = lo;
    }
#pragma unroll
    for (int it = 0; it < 2; ++it) {
      const int kb8 = vkq0 * 8 + it * 16;
      const int col = kb8 ^ vswz;
      bf16x8 hi, lo;
      split8v(vregv[it], hi, lo);
      *reinterpret_cast<bf16x8*>(&Vt[0][vdv][col]) = hi;
      *reinterpret_cast<bf16x8*>(&Vt[1][vdv][col]) = lo;
    }
  };

  const int nkt = (q0 + TQ) / TK;
  issue_loads(0);

  for (int kt = 0; kt < nkt; ++kt) {
    const int k0 = kt * TK;
    __syncthreads();  // LDS free (prev tile's reads done)
    write_tiles();
    __syncthreads();  // tile visible
    if (kt + 1 < nkt) issue_loads((kt + 1) * TK);  // T14: latency hides under compute

    if (k0 > qw + 15) continue;  // fully masked for this wave
    const bool needmask = (k0 + TK - 1 > qw);
    const int qglob = qw + li;
    bf16x8 AH[2], AL[2];

#pragma unroll
    for (int h = 0; h < 2; ++h) {
      // ---- K fragments (A-operand of S^T = K*Q^T) ----
      bf16x8 kf[2][2][2];  // [hl][ms][chunk]
#pragma unroll
      for (int hl = 0; hl < 2; ++hl)
#pragma unroll
        for (int ms = 0; ms < 2; ++ms)
#pragma unroll
          for (int c = 0; c < 2; ++c)
            kf[hl][ms][c] =
                *reinterpret_cast<const bf16x8*>(&Kl[h][hl][ms * 16 + li][c * 32 + g * 8]);

      f32x4 sT[2] = {zero4, zero4};
      __builtin_amdgcn_s_setprio(1);
#pragma unroll
      for (int ms = 0; ms < 2; ++ms)
#pragma unroll
        for (int c = 0; c < 2; ++c) {
          sT[ms] = __builtin_amdgcn_mfma_f32_16x16x32_bf16(kf[0][ms][c], qhi[h][c], sT[ms], 0, 0, 0);
          sT[ms] = __builtin_amdgcn_mfma_f32_16x16x32_bf16(kf[0][ms][c], qlo[h][c], sT[ms], 0, 0, 0);
          sT[ms] = __builtin_amdgcn_mfma_f32_16x16x32_bf16(kf[1][ms][c], qhi[h][c], sT[ms], 0, 0, 0);
        }
      __builtin_amdgcn_s_setprio(0);

      // ---- online ghostmax, head h (lane: q=li, k=16ms+4g+r) ----
      float sv[2][4];
#pragma unroll
      for (int ms = 0; ms < 2; ++ms)
#pragma unroll
        for (int r = 0; r < 4; ++r) {
          float v = sT[ms][r] * 0.125f;
          if (needmask && (k0 + ms * 16 + g * 4 + r > qglob)) v = -1e30f;
          sv[ms][r] = v;
        }
      float tmax = fmaxf(fmaxf(fmaxf(sv[0][0], sv[0][1]), fmaxf(sv[0][2], sv[0][3])),
                         fmaxf(fmaxf(sv[1][0], sv[1][1]), fmaxf(sv[1][2], sv[1][3])));
      tmax = fmaxf(tmax, __shfl_xor(tmax, 16));
      tmax = fmaxf(tmax, __shfl_xor(tmax, 32));

      if (__any(tmax > mreg[h] + 8.f)) {  // defer-max: rarely fires
        const float mnew = fmaxf(mreg[h], tmax);
        const float fh = __expf(mreg[h] - mnew);
        mreg[h] = mnew;
        lreg[h] *= fh;
        float fr[4];
#pragma unroll
        for (int r = 0; r < 4; ++r) fr[r] = __shfl(fh, 20 * g + r);
#pragma unroll
        for (int d = 0; d < 8; ++d) {
          f32x4 o = Oacc[h][d];
          o[0] *= fr[0]; o[1] *= fr[1]; o[2] *= fr[2]; o[3] *= fr[3];
          Oacc[h][d] = o;
        }
      }

      float p[2][4], psum = 0.f;
#pragma unroll
      for (int ms = 0; ms < 2; ++ms)
#pragma unroll
        for (int r = 0; r < 4; ++r) {
          p[ms][r] = __expf(sv[ms][r] - mreg[h]);
          psum += p[ms][r];
        }
      psum += __shfl_xor(psum, 16);
      psum += __shfl_xor(psum, 32);
      lreg[h] += psum;

      // ---- P -> bf16 hi/lo via per-wave LDS slice (short idx == k) ----
      {
        unsigned short h00 = f2bf(p[0][0]), h01 = f2bf(p[0][1]);
        unsigned short h02 = f2bf(p[0][2]), h03 = f2bf(p[0][3]);
        unsigned short h10 = f2bf(p[1][0]), h11 = f2bf(p[1][1]);
        unsigned short h12 = f2bf(p[1][2]), h13 = f2bf(p[1][3]);
        *reinterpret_cast<uint2*>(&Pex[w][li][g * 4]) =
            make_uint2(pack2(h00, h01), pack2(h02, h03));
        *reinterpret_cast<uint2*>(&Pex[w][li][16 + g * 4]) =
            make_uint2(pack2(h10, h11), pack2(h12, h13));
        unsigned l0 = pack2(f2bf(p[0][0] - bf2f(h00)), f2bf(p[0][1] - bf2f(h01)));
        unsigned l1 = pack2(f2bf(p[0][2] - bf2f(h02)), f2bf(p[0][3] - bf2f(h03)));
        unsigned l2 = pack2(f2bf(p[1][0] - bf2f(h10)), f2bf(p[1][1] - bf2f(h11)));
        unsigned l3 = pack2(f2bf(p[1][2] - bf2f(h12)), f2bf(p[1][3] - bf2f(h13)));
        *reinterpret_cast<uint2*>(&Pex[w][16 + li][g * 4]) = make_uint2(l0, l1);
        *reinterpret_cast<uint2*>(&Pex[w][16 + li][16 + g * 4]) = make_uint2(l2, l3);
      }
      AH[h] = *reinterpret_cast<const bf16x8*>(&Pex[w][li][g * 8]);
      AL[h] = *reinterpret_cast<const bf16x8*>(&Pex[w][16 + li][g * 8]);
    }

    // ---- PV: O += P*V  (Ph*Vh + Pl*Vh + Ph*Vl) ----
    __builtin_amdgcn_s_setprio(1);
#pragma unroll
    for (int dvt = 0; dvt < 8; ++dvt) {
      const int dvr = dvt * 16 + li;
      const int vcol = (g * 8) ^ (((dvr >> 3) & 3) << 3);
      bf16x8 vh = *reinterpret_cast<const bf16x8*>(&Vt[0][dvr][vcol]);
      bf16x8 vl = *reinterpret_cast<const bf16x8*>(&Vt[1][dvr][vcol]);
#pragma unroll
      for (int h = 0; h < 2; ++h) {
        f32x4 acc = Oacc[h][dvt];
        acc = __builtin_amdgcn_mfma_f32_16x16x32_bf16(AH[h], vh, acc, 0, 0, 0);
        acc = __builtin_amdgcn_mfma_f32_16x16x32_bf16(AL[h], vh, acc, 0, 0, 0);
        acc = __builtin_amdgcn_mfma_f32_16x16x32_bf16(AH[h], vl, acc, 0, 0, 0);
        Oacc[h][dvt] = acc;
      }
    }
    __builtin_amdgcn_s_setprio(0);
  }

  // ---- epilogue: combine heads, store, fused GroupNorm partial stats ----
  float rl0[4], rl1[4];
#pragma unroll
  for (int r = 0; r < 4; ++r) {
    rl0[r] = 1.f / __shfl(lreg[0], 20 * g + r);
    rl1[r] = lam / __shfl(lreg[1], 20 * g + r);
  }
  float* ob = Obuf + ((size_t)(b * HP_ + hp)) * S_ * DV_;
  float lsum = 0.f, lss = 0.f;
#pragma unroll
  for (int dvt = 0; dvt < 8; ++dvt)
#pragma unroll
    for (int r = 0; r < 4; ++r) {
      float vres = Oacc[0][dvt][r] * rl0[r] - Oacc[1][dvt][r] * rl1[r];
      ob[(size_t)(qw + g * 4 + r) * DV_ + dvt * 16 + li] = vres;
      lsum += vres;
      lss += vres * vres;
    }
#pragma unroll
  for (int o = 1; o < 64; o <<= 1) {
    lsum += __shfl_xor(lsum, o);
    lss += __shfl_xor(lss, o);
  }
  if (l == 0) {
    redbuf[w * 2] = lsum;
    redbuf[w * 2 + 1] = lss;
  }
  __syncthreads();
  if (tid == 0) {
    const int region = ((b * HP_ + hp) << 1) | (q0 >= 1024 ? 1 : 0);
    atomicAdd(&stats[2 * region + 0], redbuf[0] + redbuf[2] + redbuf[4] + redbuf[6]);
    atomicAdd(&stats[2 * region + 1], redbuf[1] + redbuf[3] + redbuf[5] + redbuf[7]);
  }
}

// ---------------------------------------------------------------------------
// GroupNorm apply (stats from attn epilogue; 32 contiguous 131072-f regions).
// ---------------------------------------------------------------------------
__global__ void gn_apply(const float* __restrict__ O, const float* __restrict__ stats,
                         const float* __restrict__ gw, const float* __restrict__ gb,
                         float* __restrict__ out) {
  const size_t f = ((size_t)blockIdx.x * 256 + threadIdx.x) * 4;
  const int g = (int)(f >> 17);
  const int sidx = (int)((f >> 7) & 2047);
  const int hp = (int)((f >> 18) & 7);
  const int c = hp * 128 + (sidx >> 4);
  const float mean = stats[2 * g + 0] * (1.f / 131072.f);
  const float var = stats[2 * g + 1] * (1.f / 131072.f) - mean * mean;
  const float sc = rsqrtf(var + EPSV) * gw[c] * 0.2f;  // fold (1 - lambda_init)
  const float bi = gb[c] * 0.2f;
  float4 x = *reinterpret_cast<const float4*>(O + f);
  float4 y;
  y.x = (x.x - mean) * sc + bi;
  y.y = (x.y - mean) * sc + bi;
  y.z = (x.z - mean) * sc + bi;
  y.w = (x.w - mean) * sc + bi;
  *reinterpret_cast<float4*>(out + f) = y;
}

extern "C" void kernel_launch(void* const* d_in, const int* in_sizes, int n_in,
                              void* d_out, int out_size, void* d_ws, size_t ws_size,
                              hipStream_t stream) {
  const float* q = (const float*)d_in[0];
  const float* k = (const float*)d_in[1];
  const float* v = (const float*)d_in[2];
  const float* lq1 = (const float*)d_in[3];
  const float* lk1 = (const float*)d_in[4];
  const float* lq2 = (const float*)d_in[5];
  const float* lk2 = (const float*)d_in[6];
  const float* gw = (const float*)d_in[7];
  const float* gb = (const float*)d_in[8];
  float* out = (float*)d_out;

  float* Obuf = (float*)d_ws;  // [B][HP][S][DV] fp32 = 16 MiB
  float* stats = (float*)((char*)d_ws + (size_t)B_ * HP_ * S_ * DV_ * sizeof(float));

  hipMemsetAsync(stats, 0, 64 * sizeof(float), stream);
  diffattn_fwd<<<dim3(512), dim3(256), 0, stream>>>(q, k, v, lq1, lk1, lq2, lk2, Obuf, stats);
  gn_apply<<<dim3(4096), dim3(256), 0, stream>>>(Obuf, stats, gw, gb, out);
}

// Round 7
// 286.627 us; speedup vs baseline: 1.7864x; 1.7864x over previous
//
#include <hip/hip_runtime.h>
#include <hip/hip_bf16.h>

constexpr int B_ = 2, HQ_ = 16, HP_ = 8, S_ = 2048, D_ = 64, DV_ = 128;
constexpr float LAMB0 = 0.8f;
constexpr float EPSV = 1e-5f;

constexpr int TQ = 64, TK = 32;
constexpr int KSTR = 72;  // shorts per K row (64+8) = 144 B
constexpr int VSTR = 40;  // shorts per V^T row (32+8) = 80 B

typedef __attribute__((ext_vector_type(8))) short bf16x8;
typedef __attribute__((ext_vector_type(4))) float f32x4;
typedef __attribute__((ext_vector_type(8))) float f32x8;

__device__ __forceinline__ unsigned short f2bf(float x) {
  __hip_bfloat16 h = __float2bfloat16(x);  // RNE
  unsigned short u;
  __builtin_memcpy(&u, &h, 2);
  return u;
}
__device__ __forceinline__ float bf2f(unsigned short h) {
  return __uint_as_float((unsigned)h << 16);
}
__device__ __forceinline__ unsigned pack2(unsigned short a, unsigned short b) {
  return (unsigned)a | ((unsigned)b << 16);
}
__device__ __forceinline__ void split8v(f32x8 x, bf16x8& hi, bf16x8& lo) {
  union { bf16x8 v; unsigned short s[8]; } H, L;
#pragma unroll
  for (int j = 0; j < 8; ++j) {
    unsigned short h = f2bf(x[j]);
    H.s[j] = h;
    L.s[j] = f2bf(x[j] - bf2f(h));
  }
  hi = H.v;
  lo = L.v;
}

// ---------------------------------------------------------------------------
// Differential flash attention, bf16x3 MFMA emulation.
// R7: no registers held across compute (kills the launch-bounds spiral that
// spilled 213MB to scratch in R5/R6). Single-buffered K+V LDS (38.9 KB) +
// shfl-based P exchange (no Pex LDS) -> 4 blocks/CU by LDS; latency hidden
// by TLP (16 waves/CU), not ILP. launch_bounds(256,2): no VGPR cap spills.
// ---------------------------------------------------------------------------
__launch_bounds__(256, 2)
__global__ void diffattn_fwd(const float* __restrict__ qg, const float* __restrict__ kg,
                             const float* __restrict__ vg,
                             const float* __restrict__ lq1, const float* __restrict__ lk1,
                             const float* __restrict__ lq2, const float* __restrict__ lk2,
                             float* __restrict__ Obuf, float* __restrict__ stats) {
  __shared__ short Kl[2][2][TK][KSTR];  // [head][hi/lo][k][d] 18.4 KB
  __shared__ short Vt[2][DV_][VSTR];    // [hi/lo][dv][k^swz]  20.5 KB
  __shared__ float redbuf[8];

  const int tid = threadIdx.x;
  const int w = tid >> 6;
  const int l = tid & 63;
  const int g = l >> 4;
  const int li = l & 15;

  const int t = blockIdx.x;
  const int bh = t & 15;
  const int b = bh >> 3;
  const int hp = bh & 7;
  const int u = t >> 4;
  const int qt = (u & 1) ? (31 - (u >> 1)) : (u >> 1);  // causal load pairing
  const int q0 = qt * TQ;
  const int qw = q0 + w * 16;

  float d1 = 0.f, d2 = 0.f;
  for (int i = 0; i < D_; ++i) { d1 += lq1[i] * lk1[i]; d2 += lq2[i] * lk2[i]; }
  const float lam = __expf(d1) - __expf(d2) + LAMB0;

  // ---- Q fragments in registers, hi/lo split ----
  bf16x8 qhi[2][2], qlo[2][2];
#pragma unroll
  for (int h = 0; h < 2; ++h)
#pragma unroll
    for (int c = 0; c < 2; ++c) {
      const float* p = qg + (((size_t)b * HQ_ + 2 * hp + h) * S_ + qw + li) * D_ + c * 32 + g * 8;
      f32x8 x = *reinterpret_cast<const f32x8*>(p);
      split8v(x, qhi[h][c], qlo[h][c]);
    }

  float mreg[2] = {0.f, 0.f};  // ghostmax init m=0, l=1 (implicit zero logit)
  float lreg[2] = {1.f, 1.f};
  const f32x4 zero4 = {0.f, 0.f, 0.f, 0.f};
  f32x4 Oacc[2][8];
#pragma unroll
  for (int h = 0; h < 2; ++h)
#pragma unroll
    for (int d = 0; d < 8; ++d) Oacc[h][d] = zero4;

  // staging roles
  const int khs = tid >> 7;   // K: head (128 threads each)
  const int ktf = tid & 127;
  const float* kb0 = kg + ((size_t)b * HQ_ + 2 * hp + khs) * S_ * D_;
  const int krow0 = ktf >> 3;
  const int kcol8 = (ktf & 7) * 8;
  const int vdv = tid & 127;  // V: dv lane
  const int vkq0 = tid >> 7;
  const float* vb0 = vg + ((size_t)b * HP_ + hp) * S_ * DV_ + vdv;
  const int vswz = ((vdv >> 3) & 3) << 3;

  const int nkt = (q0 + TQ) / TK;

  for (int kt = 0; kt < nkt; ++kt) {
    const int k0 = kt * TK;
    __syncthreads();  // previous tile's LDS reads complete

    // ---- stage K+V for this tile: load -> cvt -> write, nothing held ----
    {
      const float* kb = kb0 + (size_t)k0 * D_;
      f32x8 ka = *reinterpret_cast<const f32x8*>(kb + (size_t)krow0 * D_ + kcol8);
      f32x8 kc = *reinterpret_cast<const f32x8*>(kb + (size_t)(krow0 + 16) * D_ + kcol8);
      const float* vb = vb0 + (size_t)k0 * DV_;
      f32x8 va, vc;
#pragma unroll
      for (int j = 0; j < 8; ++j) va[j] = vb[(size_t)(vkq0 * 8 + j) * DV_];
#pragma unroll
      for (int j = 0; j < 8; ++j) vc[j] = vb[(size_t)(vkq0 * 8 + 16 + j) * DV_];

      bf16x8 hi, lo;
      split8v(ka, hi, lo);
      *reinterpret_cast<bf16x8*>(&Kl[khs][0][krow0][kcol8]) = hi;
      *reinterpret_cast<bf16x8*>(&Kl[khs][1][krow0][kcol8]) = lo;
      split8v(kc, hi, lo);
      *reinterpret_cast<bf16x8*>(&Kl[khs][0][krow0 + 16][kcol8]) = hi;
      *reinterpret_cast<bf16x8*>(&Kl[khs][1][krow0 + 16][kcol8]) = lo;
      split8v(va, hi, lo);
      *reinterpret_cast<bf16x8*>(&Vt[0][vdv][(vkq0 * 8) ^ vswz]) = hi;
      *reinterpret_cast<bf16x8*>(&Vt[1][vdv][(vkq0 * 8) ^ vswz]) = lo;
      split8v(vc, hi, lo);
      *reinterpret_cast<bf16x8*>(&Vt[0][vdv][(vkq0 * 8 + 16) ^ vswz]) = hi;
      *reinterpret_cast<bf16x8*>(&Vt[1][vdv][(vkq0 * 8 + 16) ^ vswz]) = lo;
    }
    __syncthreads();  // tile visible

    if (k0 > qw + 15) continue;  // fully masked for this wave
    const bool needmask = (k0 + TK - 1 > qw);
    const int qglob = qw + li;
    bf16x8 AH[2], AL[2];

#pragma unroll
    for (int h = 0; h < 2; ++h) {
      // ---- K fragments (A-operand of S^T = K*Q^T) ----
      bf16x8 kf[2][2][2];  // [hl][ms][chunk]
#pragma unroll
      for (int hl = 0; hl < 2; ++hl)
#pragma unroll
        for (int ms = 0; ms < 2; ++ms)
#pragma unroll
          for (int c = 0; c < 2; ++c)
            kf[hl][ms][c] =
                *reinterpret_cast<const bf16x8*>(&Kl[h][hl][ms * 16 + li][c * 32 + g * 8]);

      f32x4 sT[2] = {zero4, zero4};
      __builtin_amdgcn_s_setprio(1);
#pragma unroll
      for (int ms = 0; ms < 2; ++ms)
#pragma unroll
        for (int c = 0; c < 2; ++c) {
          sT[ms] = __builtin_amdgcn_mfma_f32_16x16x32_bf16(kf[0][ms][c], qhi[h][c], sT[ms], 0, 0, 0);
          sT[ms] = __builtin_amdgcn_mfma_f32_16x16x32_bf16(kf[0][ms][c], qlo[h][c], sT[ms], 0, 0, 0);
          sT[ms] = __builtin_amdgcn_mfma_f32_16x16x32_bf16(kf[1][ms][c], qhi[h][c], sT[ms], 0, 0, 0);
        }
      __builtin_amdgcn_s_setprio(0);

      // ---- online ghostmax, head h (lane: q=li, k=16ms+4g+r) ----
      float sv[2][4];
#pragma unroll
      for (int ms = 0; ms < 2; ++ms)
#pragma unroll
        for (int r = 0; r < 4; ++r) {
          float v = sT[ms][r] * 0.125f;
          if (needmask && (k0 + ms * 16 + g * 4 + r > qglob)) v = -1e30f;
          sv[ms][r] = v;
        }
      float tmax = fmaxf(fmaxf(fmaxf(sv[0][0], sv[0][1]), fmaxf(sv[0][2], sv[0][3])),
                         fmaxf(fmaxf(sv[1][0], sv[1][1]), fmaxf(sv[1][2], sv[1][3])));
      tmax = fmaxf(tmax, __shfl_xor(tmax, 16));
      tmax = fmaxf(tmax, __shfl_xor(tmax, 32));

      if (__any(tmax > mreg[h] + 8.f)) {  // defer-max: rarely fires
        const float mnew = fmaxf(mreg[h], tmax);
        const float fh = __expf(mreg[h] - mnew);
        mreg[h] = mnew;
        lreg[h] *= fh;
        float fr[4];
#pragma unroll
        for (int r = 0; r < 4; ++r) fr[r] = __shfl(fh, 20 * g + r);
#pragma unroll
        for (int d = 0; d < 8; ++d) {
          f32x4 o = Oacc[h][d];
          o[0] *= fr[0]; o[1] *= fr[1]; o[2] *= fr[2]; o[3] *= fr[3];
          Oacc[h][d] = o;
        }
      }

      float p[2][4], psum = 0.f;
#pragma unroll
      for (int ms = 0; ms < 2; ++ms)
#pragma unroll
        for (int r = 0; r < 4; ++r) {
          p[ms][r] = __expf(sv[ms][r] - mreg[h]);
          psum += p[ms][r];
        }
      psum += __shfl_xor(psum, 16);
      psum += __shfl_xor(psum, 32);
      lreg[h] += psum;

      // ---- P -> bf16 hi/lo, shfl lane-exchange into PV A-fragment layout ----
      unsigned ph0a = pack2(f2bf(p[0][0]), f2bf(p[0][1]));
      unsigned ph0b = pack2(f2bf(p[0][2]), f2bf(p[0][3]));
      unsigned ph1a = pack2(f2bf(p[1][0]), f2bf(p[1][1]));
      unsigned ph1b = pack2(f2bf(p[1][2]), f2bf(p[1][3]));
      float pl[2][4];
#pragma unroll
      for (int ms = 0; ms < 2; ++ms)
#pragma unroll
        for (int r = 0; r < 4; ++r) pl[ms][r] = p[ms][r] - bf2f(f2bf(p[ms][r]));
      unsigned pl0a = pack2(f2bf(pl[0][0]), f2bf(pl[0][1]));
      unsigned pl0b = pack2(f2bf(pl[0][2]), f2bf(pl[0][3]));
      unsigned pl1a = pack2(f2bf(pl[1][0]), f2bf(pl[1][1]));
      unsigned pl1b = pack2(f2bf(pl[1][2]), f2bf(pl[1][3]));

      const int srcA = 32 * (g & 1) + li;
      const int srcB = srcA + 16;
      const bool hiMs = (g >> 1) != 0;
      union { bf16x8 v; unsigned us[4]; } AHu, ALu;
      {
        unsigned a0 = (unsigned)__shfl((int)ph0a, srcA), b0 = (unsigned)__shfl((int)ph1a, srcA);
        unsigned a1 = (unsigned)__shfl((int)ph0b, srcA), b1 = (unsigned)__shfl((int)ph1b, srcA);
        unsigned a2 = (unsigned)__shfl((int)ph0a, srcB), b2 = (unsigned)__shfl((int)ph1a, srcB);
        unsigned a3 = (unsigned)__shfl((int)ph0b, srcB), b3 = (unsigned)__shfl((int)ph1b, srcB);
        AHu.us[0] = hiMs ? b0 : a0; AHu.us[1] = hiMs ? b1 : a1;
        AHu.us[2] = hiMs ? b2 : a2; AHu.us[3] = hiMs ? b3 : a3;
      }
      {
        unsigned a0 = (unsigned)__shfl((int)pl0a, srcA), b0 = (unsigned)__shfl((int)pl1a, srcA);
        unsigned a1 = (unsigned)__shfl((int)pl0b, srcA), b1 = (unsigned)__shfl((int)pl1b, srcA);
        unsigned a2 = (unsigned)__shfl((int)pl0a, srcB), b2 = (unsigned)__shfl((int)pl1a, srcB);
        unsigned a3 = (unsigned)__shfl((int)pl0b, srcB), b3 = (unsigned)__shfl((int)pl1b, srcB);
        ALu.us[0] = hiMs ? b0 : a0; ALu.us[1] = hiMs ? b1 : a1;
        ALu.us[2] = hiMs ? b2 : a2; ALu.us[3] = hiMs ? b3 : a3;
      }
      AH[h] = AHu.v;
      AL[h] = ALu.v;
    }

    // ---- PV: O += P*V  (Ph*Vh + Pl*Vh + Ph*Vl) ----
    __builtin_amdgcn_s_setprio(1);
#pragma unroll
    for (int dvt = 0; dvt < 8; ++dvt) {
      const int dvr = dvt * 16 + li;
      const int vcol = (g * 8) ^ (((dvr >> 3) & 3) << 3);
      bf16x8 vh = *reinterpret_cast<const bf16x8*>(&Vt[0][dvr][vcol]);
      bf16x8 vl = *reinterpret_cast<const bf16x8*>(&Vt[1][dvr][vcol]);
#pragma unroll
      for (int h = 0; h < 2; ++h) {
        f32x4 acc = Oacc[h][dvt];
        acc = __builtin_amdgcn_mfma_f32_16x16x32_bf16(AH[h], vh, acc, 0, 0, 0);
        acc = __builtin_amdgcn_mfma_f32_16x16x32_bf16(AL[h], vh, acc, 0, 0, 0);
        acc = __builtin_amdgcn_mfma_f32_16x16x32_bf16(AH[h], vl, acc, 0, 0, 0);
        Oacc[h][dvt] = acc;
      }
    }
    __builtin_amdgcn_s_setprio(0);
  }

  // ---- epilogue: combine heads, store, fused GroupNorm partial stats ----
  float rl0[4], rl1[4];
#pragma unroll
  for (int r = 0; r < 4; ++r) {
    rl0[r] = 1.f / __shfl(lreg[0], 20 * g + r);
    rl1[r] = lam / __shfl(lreg[1], 20 * g + r);
  }
  float* ob = Obuf + ((size_t)(b * HP_ + hp)) * S_ * DV_;
  float lsum = 0.f, lss = 0.f;
#pragma unroll
  for (int dvt = 0; dvt < 8; ++dvt)
#pragma unroll
    for (int r = 0; r < 4; ++r) {
      float vres = Oacc[0][dvt][r] * rl0[r] - Oacc[1][dvt][r] * rl1[r];
      ob[(size_t)(qw + g * 4 + r) * DV_ + dvt * 16 + li] = vres;
      lsum += vres;
      lss += vres * vres;
    }
#pragma unroll
  for (int o = 1; o < 64; o <<= 1) {
    lsum += __shfl_xor(lsum, o);
    lss += __shfl_xor(lss, o);
  }
  if (l == 0) {
    redbuf[w * 2] = lsum;
    redbuf[w * 2 + 1] = lss;
  }
  __syncthreads();
  if (tid == 0) {
    const int region = ((b * HP_ + hp) << 1) | (q0 >= 1024 ? 1 : 0);
    atomicAdd(&stats[2 * region + 0], redbuf[0] + redbuf[2] + redbuf[4] + redbuf[6]);
    atomicAdd(&stats[2 * region + 1], redbuf[1] + redbuf[3] + redbuf[5] + redbuf[7]);
  }
}

// ---------------------------------------------------------------------------
// GroupNorm apply (stats from attn epilogue; 32 contiguous 131072-f regions).
// ---------------------------------------------------------------------------
__global__ void gn_apply(const float* __restrict__ O, const float* __restrict__ stats,
                         const float* __restrict__ gw, const float* __restrict__ gb,
                         float* __restrict__ out) {
  const size_t f = ((size_t)blockIdx.x * 256 + threadIdx.x) * 4;
  const int g = (int)(f >> 17);
  const int sidx = (int)((f >> 7) & 2047);
  const int hp = (int)((f >> 18) & 7);
  const int c = hp * 128 + (sidx >> 4);
  const float mean = stats[2 * g + 0] * (1.f / 131072.f);
  const float var = stats[2 * g + 1] * (1.f / 131072.f) - mean * mean;
  const float sc = rsqrtf(var + EPSV) * gw[c] * 0.2f;  // fold (1 - lambda_init)
  const float bi = gb[c] * 0.2f;
  float4 x = *reinterpret_cast<const float4*>(O + f);
  float4 y;
  y.x = (x.x - mean) * sc + bi;
  y.y = (x.y - mean) * sc + bi;
  y.z = (x.z - mean) * sc + bi;
  y.w = (x.w - mean) * sc + bi;
  *reinterpret_cast<float4*>(out + f) = y;
}

extern "C" void kernel_launch(void* const* d_in, const int* in_sizes, int n_in,
                              void* d_out, int out_size, void* d_ws, size_t ws_size,
                              hipStream_t stream) {
  const float* q = (const float*)d_in[0];
  const float* k = (const float*)d_in[1];
  const float* v = (const float*)d_in[2];
  const float* lq1 = (const float*)d_in[3];
  const float* lk1 = (const float*)d_in[4];
  const float* lq2 = (const float*)d_in[5];
  const float* lk2 = (const float*)d_in[6];
  const float* gw = (const float*)d_in[7];
  const float* gb = (const float*)d_in[8];
  float* out = (float*)d_out;

  float* Obuf = (float*)d_ws;  // [B][HP][S][DV] fp32 = 16 MiB
  float* stats = (float*)((char*)d_ws + (size_t)B_ * HP_ * S_ * DV_ * sizeof(float));

  hipMemsetAsync(stats, 0, 64 * sizeof(float), stream);
  diffattn_fwd<<<dim3(512), dim3(256), 0, stream>>>(q, k, v, lq1, lk1, lq2, lk2, Obuf, stats);
  gn_apply<<<dim3(4096), dim3(256), 0, stream>>>(Obuf, stats, gw, gb, out);
}

// Round 8
// 275.141 us; speedup vs baseline: 1.8610x; 1.0417x over previous
//
#include <hip/hip_runtime.h>
#include <hip/hip_bf16.h>

constexpr int B_ = 2, HQ_ = 16, HP_ = 8, S_ = 2048, D_ = 64, DV_ = 128;
constexpr float LAMB0 = 0.8f;
constexpr float EPSV = 1e-5f;

constexpr int TQ = 64, TK = 32;
constexpr int KSTR = 72;  // shorts per K row (64+8) = 144 B
constexpr int VSTR = 40;  // shorts per V^T row (32+8) = 80 B

typedef __attribute__((ext_vector_type(8))) short bf16x8;
typedef __attribute__((ext_vector_type(4))) float f32x4;
typedef __attribute__((ext_vector_type(8))) float f32x8;

__device__ __forceinline__ unsigned short f2bf(float x) {
  __hip_bfloat16 h = __float2bfloat16(x);  // RNE
  unsigned short u;
  __builtin_memcpy(&u, &h, 2);
  return u;
}
__device__ __forceinline__ float bf2f(unsigned short h) {
  return __uint_as_float((unsigned)h << 16);
}
__device__ __forceinline__ unsigned pack2(unsigned short a, unsigned short b) {
  return (unsigned)a | ((unsigned)b << 16);
}
__device__ __forceinline__ void split8v(f32x8 x, bf16x8& hi, bf16x8& lo) {
  union { bf16x8 v; unsigned short s[8]; } H, L;
#pragma unroll
  for (int j = 0; j < 8; ++j) {
    unsigned short h = f2bf(x[j]);
    H.s[j] = h;
    L.s[j] = f2bf(x[j] - bf2f(h));
  }
  hi = H.v;
  lo = L.v;
}

// ---------------------------------------------------------------------------
// Differential flash attention, bf16x3 MFMA emulation.
// R8: HEAD-SPLIT 8-wave blocks. Grid is fixed at 512 (q-tiles), which capped
// total waves at 2048 (25% of chip) — the R7 bottleneck. Now each block has
// 512 threads: waves 0-3 = head 0, waves 4-7 = head 1, sharing one staged
// K/V tile (38.9 KB, single-buffered). 4096 waves total, halved per-wave
// VGPR state (one head each), staging work per thread halved. Heads combine
// at the end through an LDS buffer aliased over the staging area.
// ---------------------------------------------------------------------------
__launch_bounds__(512, 4)
__global__ void diffattn_fwd(const float* __restrict__ qg, const float* __restrict__ kg,
                             const float* __restrict__ vg,
                             const float* __restrict__ lq1, const float* __restrict__ lk1,
                             const float* __restrict__ lq2, const float* __restrict__ lk2,
                             float* __restrict__ Obuf, float* __restrict__ stats) {
  __shared__ __align__(16) char smem[38912];  // staging / merge union
  auto Kl = reinterpret_cast<short(*)[2][TK][KSTR]>(smem);        // [head][hl][k][d] 18.4 KB
  auto Vt = reinterpret_cast<short(*)[DV_][VSTR]>(smem + 18432);  // [hl][dv][k^swz] 20.5 KB
  float* mbuf = reinterpret_cast<float*>(smem);                   // merge: 4*32*64 f = 32 KB
  __shared__ float redbuf[8];

  const int tid = threadIdx.x;
  const int w = tid >> 6;      // 0..7
  const int hw = w >> 2;       // head of this wave
  const int qs = w & 3;        // q-strip
  const int l = tid & 63;
  const int g = l >> 4;
  const int li = l & 15;

  const int t = blockIdx.x;
  const int bh = t & 15;
  const int b = bh >> 3;
  const int hp = bh & 7;
  const int u = t >> 4;
  const int qt = (u & 1) ? (31 - (u >> 1)) : (u >> 1);  // causal load pairing
  const int q0 = qt * TQ;
  const int qw = q0 + qs * 16;

  float d1 = 0.f, d2 = 0.f;
  for (int i = 0; i < D_; ++i) { d1 += lq1[i] * lk1[i]; d2 += lq2[i] * lk2[i]; }
  const float lam = __expf(d1) - __expf(d2) + LAMB0;

  // ---- Q fragments (this wave's head only), hi/lo split ----
  bf16x8 qhi[2], qlo[2];
#pragma unroll
  for (int c = 0; c < 2; ++c) {
    const float* p = qg + (((size_t)b * HQ_ + 2 * hp + hw) * S_ + qw + li) * D_ + c * 32 + g * 8;
    f32x8 x = *reinterpret_cast<const f32x8*>(p);
    split8v(x, qhi[c], qlo[c]);
  }

  float mreg = 0.f;  // ghostmax init m=0, l=1 (implicit zero logit)
  float lreg = 1.f;
  const f32x4 zero4 = {0.f, 0.f, 0.f, 0.f};
  f32x4 Oacc[8];
#pragma unroll
  for (int d = 0; d < 8; ++d) Oacc[d] = zero4;

  // staging roles (512 threads: K 4096 floats + V 4096 floats, 8+8 per thread)
  const int khs = tid >> 8;            // K: head
  const int kidx = tid & 255;
  const int krow = kidx >> 3;          // 0..31
  const int kcol8 = (kidx & 7) * 8;
  const float* kb0 = kg + ((size_t)b * HQ_ + 2 * hp + khs) * S_ * D_;
  const int vdv = tid & 127;           // V: dv lane
  const int vk8 = (tid >> 7) * 8;      // 0,8,16,24
  const float* vb0 = vg + ((size_t)b * HP_ + hp) * S_ * DV_ + vdv;
  const int vswz = ((vdv >> 3) & 3) << 3;

  const int nkt = (q0 + TQ) / TK;

  for (int kt = 0; kt < nkt; ++kt) {
    const int k0 = kt * TK;
    __syncthreads();  // previous tile's LDS reads complete

    // ---- stage K+V: load -> cvt -> write, nothing held across compute ----
    {
      f32x8 kx = *reinterpret_cast<const f32x8*>(kb0 + (size_t)(k0 + krow) * D_ + kcol8);
      const float* vb = vb0 + (size_t)k0 * DV_;
      f32x8 vx;
#pragma unroll
      for (int j = 0; j < 8; ++j) vx[j] = vb[(size_t)(vk8 + j) * DV_];
      bf16x8 hi, lo;
      split8v(kx, hi, lo);
      *reinterpret_cast<bf16x8*>(&Kl[khs][0][krow][kcol8]) = hi;
      *reinterpret_cast<bf16x8*>(&Kl[khs][1][krow][kcol8]) = lo;
      split8v(vx, hi, lo);
      *reinterpret_cast<bf16x8*>(&Vt[0][vdv][vk8 ^ vswz]) = hi;
      *reinterpret_cast<bf16x8*>(&Vt[1][vdv][vk8 ^ vswz]) = lo;
    }
    __syncthreads();  // tile visible

    if (k0 > qw + 15) continue;  // fully masked for this wave
    const bool needmask = (k0 + TK - 1 > qw);
    const int qglob = qw + li;

    // ---- K fragments (A-operand of S^T = K*Q^T), this head ----
    bf16x8 kf[2][2][2];  // [hl][ms][chunk]
#pragma unroll
    for (int hl = 0; hl < 2; ++hl)
#pragma unroll
      for (int ms = 0; ms < 2; ++ms)
#pragma unroll
        for (int c = 0; c < 2; ++c)
          kf[hl][ms][c] =
              *reinterpret_cast<const bf16x8*>(&Kl[hw][hl][ms * 16 + li][c * 32 + g * 8]);

    f32x4 sT[2] = {zero4, zero4};
    __builtin_amdgcn_s_setprio(1);
#pragma unroll
    for (int ms = 0; ms < 2; ++ms)
#pragma unroll
      for (int c = 0; c < 2; ++c) {
        sT[ms] = __builtin_amdgcn_mfma_f32_16x16x32_bf16(kf[0][ms][c], qhi[c], sT[ms], 0, 0, 0);
        sT[ms] = __builtin_amdgcn_mfma_f32_16x16x32_bf16(kf[0][ms][c], qlo[c], sT[ms], 0, 0, 0);
        sT[ms] = __builtin_amdgcn_mfma_f32_16x16x32_bf16(kf[1][ms][c], qhi[c], sT[ms], 0, 0, 0);
      }
    __builtin_amdgcn_s_setprio(0);

    // ---- online ghostmax (lane: q=li, k=16ms+4g+r) ----
    float sv[2][4];
#pragma unroll
    for (int ms = 0; ms < 2; ++ms)
#pragma unroll
      for (int r = 0; r < 4; ++r) {
        float v = sT[ms][r] * 0.125f;
        if (needmask && (k0 + ms * 16 + g * 4 + r > qglob)) v = -1e30f;
        sv[ms][r] = v;
      }
    float tmax = fmaxf(fmaxf(fmaxf(sv[0][0], sv[0][1]), fmaxf(sv[0][2], sv[0][3])),
                       fmaxf(fmaxf(sv[1][0], sv[1][1]), fmaxf(sv[1][2], sv[1][3])));
    tmax = fmaxf(tmax, __shfl_xor(tmax, 16));
    tmax = fmaxf(tmax, __shfl_xor(tmax, 32));

    if (__any(tmax > mreg + 8.f)) {  // defer-max: rarely fires
      const float mnew = fmaxf(mreg, tmax);
      const float fh = __expf(mreg - mnew);
      mreg = mnew;
      lreg *= fh;
      float fr[4];
#pragma unroll
      for (int r = 0; r < 4; ++r) fr[r] = __shfl(fh, 20 * g + r);
#pragma unroll
      for (int d = 0; d < 8; ++d) {
        f32x4 o = Oacc[d];
        o[0] *= fr[0]; o[1] *= fr[1]; o[2] *= fr[2]; o[3] *= fr[3];
        Oacc[d] = o;
      }
    }

    float p[2][4], psum = 0.f;
#pragma unroll
    for (int ms = 0; ms < 2; ++ms)
#pragma unroll
      for (int r = 0; r < 4; ++r) {
        p[ms][r] = __expf(sv[ms][r] - mreg);
        psum += p[ms][r];
      }
    psum += __shfl_xor(psum, 16);
    psum += __shfl_xor(psum, 32);
    lreg += psum;

    // ---- P -> bf16 hi/lo, shfl lane-exchange into PV A-fragment layout ----
    unsigned ph0a = pack2(f2bf(p[0][0]), f2bf(p[0][1]));
    unsigned ph0b = pack2(f2bf(p[0][2]), f2bf(p[0][3]));
    unsigned ph1a = pack2(f2bf(p[1][0]), f2bf(p[1][1]));
    unsigned ph1b = pack2(f2bf(p[1][2]), f2bf(p[1][3]));
    float pl[2][4];
#pragma unroll
    for (int ms = 0; ms < 2; ++ms)
#pragma unroll
      for (int r = 0; r < 4; ++r) pl[ms][r] = p[ms][r] - bf2f(f2bf(p[ms][r]));
    unsigned pl0a = pack2(f2bf(pl[0][0]), f2bf(pl[0][1]));
    unsigned pl0b = pack2(f2bf(pl[0][2]), f2bf(pl[0][3]));
    unsigned pl1a = pack2(f2bf(pl[1][0]), f2bf(pl[1][1]));
    unsigned pl1b = pack2(f2bf(pl[1][2]), f2bf(pl[1][3]));

    const int srcA = 32 * (g & 1) + li;
    const int srcB = srcA + 16;
    const bool hiMs = (g >> 1) != 0;
    bf16x8 AH, AL;
    {
      union { bf16x8 v; unsigned us[4]; } U;
      unsigned a0 = (unsigned)__shfl((int)ph0a, srcA), b0 = (unsigned)__shfl((int)ph1a, srcA);
      unsigned a1 = (unsigned)__shfl((int)ph0b, srcA), b1 = (unsigned)__shfl((int)ph1b, srcA);
      unsigned a2 = (unsigned)__shfl((int)ph0a, srcB), b2 = (unsigned)__shfl((int)ph1a, srcB);
      unsigned a3 = (unsigned)__shfl((int)ph0b, srcB), b3 = (unsigned)__shfl((int)ph1b, srcB);
      U.us[0] = hiMs ? b0 : a0; U.us[1] = hiMs ? b1 : a1;
      U.us[2] = hiMs ? b2 : a2; U.us[3] = hiMs ? b3 : a3;
      AH = U.v;
    }
    {
      union { bf16x8 v; unsigned us[4]; } U;
      unsigned a0 = (unsigned)__shfl((int)pl0a, srcA), b0 = (unsigned)__shfl((int)pl1a, srcA);
      unsigned a1 = (unsigned)__shfl((int)pl0b, srcA), b1 = (unsigned)__shfl((int)pl1b, srcA);
      unsigned a2 = (unsigned)__shfl((int)pl0a, srcB), b2 = (unsigned)__shfl((int)pl1a, srcB);
      unsigned a3 = (unsigned)__shfl((int)pl0b, srcB), b3 = (unsigned)__shfl((int)pl1b, srcB);
      U.us[0] = hiMs ? b0 : a0; U.us[1] = hiMs ? b1 : a1;
      U.us[2] = hiMs ? b2 : a2; U.us[3] = hiMs ? b3 : a3;
      AL = U.v;
    }

    // ---- PV: O += P*V  (Ph*Vh + Pl*Vh + Ph*Vl) ----
    __builtin_amdgcn_s_setprio(1);
#pragma unroll
    for (int dvt = 0; dvt < 8; ++dvt) {
      const int dvr = dvt * 16 + li;
      const int vcol = (g * 8) ^ (((dvr >> 3) & 3) << 3);
      bf16x8 vh = *reinterpret_cast<const bf16x8*>(&Vt[0][dvr][vcol]);
      bf16x8 vl = *reinterpret_cast<const bf16x8*>(&Vt[1][dvr][vcol]);
      f32x4 acc = Oacc[dvt];
      acc = __builtin_amdgcn_mfma_f32_16x16x32_bf16(AH, vh, acc, 0, 0, 0);
      acc = __builtin_amdgcn_mfma_f32_16x16x32_bf16(AL, vh, acc, 0, 0, 0);
      acc = __builtin_amdgcn_mfma_f32_16x16x32_bf16(AH, vl, acc, 0, 0, 0);
      Oacc[dvt] = acc;
    }
    __builtin_amdgcn_s_setprio(0);
  }

  // ---- epilogue: head 1 publishes lam*O1/l1 via LDS; head 0 combines ----
  __syncthreads();  // staging LDS free -> reuse as merge buffer
  if (w >= 4) {
    float rl[4];
#pragma unroll
    for (int r = 0; r < 4; ++r) rl[r] = lam / __shfl(lreg, 20 * g + r);
#pragma unroll
    for (int dvt = 0; dvt < 8; ++dvt)
#pragma unroll
      for (int r = 0; r < 4; ++r)
        mbuf[((qs * 32 + dvt * 4 + r) * 64) + l] = Oacc[dvt][r] * rl[r];
  }
  __syncthreads();

  float lsum = 0.f, lss = 0.f;
  if (w < 4) {
    float rl[4];
#pragma unroll
    for (int r = 0; r < 4; ++r) rl[r] = 1.f / __shfl(lreg, 20 * g + r);
    float* ob = Obuf + ((size_t)(b * HP_ + hp)) * S_ * DV_;
#pragma unroll
    for (int dvt = 0; dvt < 8; ++dvt)
#pragma unroll
      for (int r = 0; r < 4; ++r) {
        float vres = Oacc[dvt][r] * rl[r] - mbuf[((qs * 32 + dvt * 4 + r) * 64) + l];
        ob[(size_t)(qw + g * 4 + r) * DV_ + dvt * 16 + li] = vres;
        lsum += vres;
        lss += vres * vres;
      }
#pragma unroll
    for (int o = 1; o < 64; o <<= 1) {
      lsum += __shfl_xor(lsum, o);
      lss += __shfl_xor(lss, o);
    }
    if (l == 0) {
      redbuf[w * 2] = lsum;
      redbuf[w * 2 + 1] = lss;
    }
  }
  __syncthreads();
  if (tid == 0) {
    const int region = ((b * HP_ + hp) << 1) | (q0 >= 1024 ? 1 : 0);
    atomicAdd(&stats[2 * region + 0], redbuf[0] + redbuf[2] + redbuf[4] + redbuf[6]);
    atomicAdd(&stats[2 * region + 1], redbuf[1] + redbuf[3] + redbuf[5] + redbuf[7]);
  }
}

// ---------------------------------------------------------------------------
// GroupNorm apply (stats from attn epilogue; 32 contiguous 131072-f regions).
// ---------------------------------------------------------------------------
__global__ void gn_apply(const float* __restrict__ O, const float* __restrict__ stats,
                         const float* __restrict__ gw, const float* __restrict__ gb,
                         float* __restrict__ out) {
  const size_t f = ((size_t)blockIdx.x * 256 + threadIdx.x) * 4;
  const int g = (int)(f >> 17);
  const int sidx = (int)((f >> 7) & 2047);
  const int hp = (int)((f >> 18) & 7);
  const int c = hp * 128 + (sidx >> 4);
  const float mean = stats[2 * g + 0] * (1.f / 131072.f);
  const float var = stats[2 * g + 1] * (1.f / 131072.f) - mean * mean;
  const float sc = rsqrtf(var + EPSV) * gw[c] * 0.2f;  // fold (1 - lambda_init)
  const float bi = gb[c] * 0.2f;
  float4 x = *reinterpret_cast<const float4*>(O + f);
  float4 y;
  y.x = (x.x - mean) * sc + bi;
  y.y = (x.y - mean) * sc + bi;
  y.z = (x.z - mean) * sc + bi;
  y.w = (x.w - mean) * sc + bi;
  *reinterpret_cast<float4*>(out + f) = y;
}

extern "C" void kernel_launch(void* const* d_in, const int* in_sizes, int n_in,
                              void* d_out, int out_size, void* d_ws, size_t ws_size,
                              hipStream_t stream) {
  const float* q = (const float*)d_in[0];
  const float* k = (const float*)d_in[1];
  const float* v = (const float*)d_in[2];
  const float* lq1 = (const float*)d_in[3];
  const float* lk1 = (const float*)d_in[4];
  const float* lq2 = (const float*)d_in[5];
  const float* lk2 = (const float*)d_in[6];
  const float* gw = (const float*)d_in[7];
  const float* gb = (const float*)d_in[8];
  float* out = (float*)d_out;

  float* Obuf = (float*)d_ws;  // [B][HP][S][DV] fp32 = 16 MiB
  float* stats = (float*)((char*)d_ws + (size_t)B_ * HP_ * S_ * DV_ * sizeof(float));

  hipMemsetAsync(stats, 0, 64 * sizeof(float), stream);
  diffattn_fwd<<<dim3(512), dim3(512), 0, stream>>>(q, k, v, lq1, lk1, lq2, lk2, Obuf, stats);
  gn_apply<<<dim3(4096), dim3(256), 0, stream>>>(Obuf, stats, gw, gb, out);
}